// Round 1
// baseline (490.643 us; speedup 1.0000x reference)
//
#include <hip/hip_runtime.h>
#include <hip/hip_bf16.h>
#include <math.h>

// Bahdanau attention + reservoir RNN cell, fused pipeline:
//  K0: Ua_w f32 -> bf16 (ws)
//  K1: q = h_prev@Wa^T + Wa_b + Ua_b  (fold Ua_b in; Va_b dropped: softmax-invariant)
//  K2: per (b, 128-row s-chunk): bf16 MFMA GEMM k=x_ref@Ua^T (N=512 in regs),
//      tanh(q+k)·Va -> scores, partial softmax (m,l), partial context (L2 re-read)
//  K3: exact combine of 16 partials per b -> context (to d_out + ws)
//  K4: h_next = tanh([x_t,ctx]@Wih^T + b + h_prev@Whh^T + b) (to d_out)

typedef __attribute__((ext_vector_type(8))) short short8;
typedef __attribute__((ext_vector_type(8))) unsigned short ushort8;
typedef __attribute__((ext_vector_type(4))) unsigned short us4;
typedef __attribute__((ext_vector_type(4))) float f32x4;

#define S_LEN 2048
#define BDIM 128
#define HDIM 512
#define EDIM 512
#define BM 128
#define BK 64
#define NCHUNK (S_LEN / BM)  // 16

__device__ __forceinline__ unsigned short f2bf(float f) {
  unsigned int u = __float_as_uint(f);
  u += 0x7fffu + ((u >> 16) & 1u);  // RNE
  return (unsigned short)(u >> 16);
}

__device__ __forceinline__ float fast_tanh(float x) {
  float e = __expf(2.0f * x);
  return 1.0f - 2.0f / (e + 1.0f);  // saturates correctly for |x| large
}

__global__ __launch_bounds__(256) void k_cvt(const float* __restrict__ src,
                                             unsigned short* __restrict__ dst, int n4) {
  int i = blockIdx.x * blockDim.x + threadIdx.x;
  if (i < n4) {
    float4 v = ((const float4*)src)[i];
    us4 p;
    p[0] = f2bf(v.x); p[1] = f2bf(v.y); p[2] = f2bf(v.z); p[3] = f2bf(v.w);
    ((us4*)dst)[i] = p;
  }
}

__global__ __launch_bounds__(512) void k_q(const float* __restrict__ hp,
                                           const float* __restrict__ Wa,
                                           const float* __restrict__ Wab,
                                           const float* __restrict__ Uab,
                                           float* __restrict__ q) {
  int b = blockIdx.x, o = threadIdx.x;
  __shared__ float hs[HDIM];
  hs[o] = hp[b * HDIM + o];
  __syncthreads();
  const float4* wr = (const float4*)(Wa + (long)o * HDIM);
  float acc = 0.f;
#pragma unroll 8
  for (int i = 0; i < HDIM / 4; ++i) {
    float4 v = wr[i];
    acc += v.x * hs[i * 4 + 0] + v.y * hs[i * 4 + 1] + v.z * hs[i * 4 + 2] + v.w * hs[i * 4 + 3];
  }
  q[b * HDIM + o] = acc + Wab[o] + Uab[o];
}

__global__ __launch_bounds__(512) void k_scores_ctx(
    const float* __restrict__ xref, const unsigned short* __restrict__ uab,
    const float* __restrict__ q, const float* __restrict__ va,
    float* __restrict__ mArr, float* __restrict__ lArr, float* __restrict__ cpart) {
  int chunk = blockIdx.x;
  int b = blockIdx.y;
  int tid = threadIdx.x;
  int lane = tid & 63;
  int w = tid >> 6;
  int s0 = chunk * BM;

  __shared__ unsigned short Ab[BM * BK];    // 16 KB, XOR-swizzled 16B slots
  __shared__ unsigned short Bb[HDIM * BK];  // 64 KB, XOR-swizzled
  __shared__ float sc[BM];
  __shared__ float pl[BM];
  __shared__ float red1[8], red2[8], bc[1];

  if (tid < BM) sc[tid] = 0.0f;

  f32x4 acc[8][4];
#pragma unroll
  for (int m = 0; m < 8; ++m)
#pragma unroll
    for (int n = 0; n < 4; ++n) acc[m][n] = f32x4{0.f, 0.f, 0.f, 0.f};

  const float* xb = xref + ((long)b * S_LEN + s0) * HDIM;

  for (int kc = 0; kc < HDIM / BK; ++kc) {
    __syncthreads();  // protect LDS from previous iter's readers
    // stage A: 128 rows x 64 k, f32 -> bf16 (2x 8-float groups / thread)
#pragma unroll
    for (int i = 0; i < 2; ++i) {
      int g = tid + i * 512;
      int row = g >> 3, slot = g & 7;
      const float* src = xb + (long)row * HDIM + kc * BK + slot * 8;
      float4 v0 = ((const float4*)src)[0];
      float4 v1 = ((const float4*)src)[1];
      ushort8 pk;
      pk[0] = f2bf(v0.x); pk[1] = f2bf(v0.y); pk[2] = f2bf(v0.z); pk[3] = f2bf(v0.w);
      pk[4] = f2bf(v1.x); pk[5] = f2bf(v1.y); pk[6] = f2bf(v1.z); pk[7] = f2bf(v1.w);
      *(ushort8*)&Ab[row * BK + ((slot ^ (row & 7)) * 8)] = pk;
    }
    // stage B: Ua bf16, 512 rows x 64 k (8x 8-elem groups / thread)
#pragma unroll
    for (int i = 0; i < 8; ++i) {
      int g = tid + i * 512;
      int row = g >> 3, slot = g & 7;
      ushort8 v = *(const ushort8*)(uab + (long)row * HDIM + kc * BK + slot * 8);
      *(ushort8*)&Bb[row * BK + ((slot ^ (row & 7)) * 8)] = v;
    }
    __syncthreads();
    // B fragments for this wave's 64 output cols
    short8 bf[4][2];
#pragma unroll
    for (int n = 0; n < 4; ++n)
#pragma unroll
      for (int kk = 0; kk < 2; ++kk) {
        int row = w * 64 + n * 16 + (lane & 15);
        int slot = (kk * 4 + (lane >> 4)) ^ (row & 7);
        bf[n][kk] = *(const short8*)&Bb[row * BK + slot * 8];
      }
#pragma unroll
    for (int m = 0; m < 8; ++m) {
      short8 af[2];
#pragma unroll
      for (int kk = 0; kk < 2; ++kk) {
        int row = m * 16 + (lane & 15);
        int slot = (kk * 4 + (lane >> 4)) ^ (row & 7);
        af[kk] = *(const short8*)&Ab[row * BK + slot * 8];
      }
#pragma unroll
      for (int n = 0; n < 4; ++n) {
        acc[m][n] = __builtin_amdgcn_mfma_f32_16x16x32_bf16(af[0], bf[n][0], acc[m][n], 0, 0, 0);
        acc[m][n] = __builtin_amdgcn_mfma_f32_16x16x32_bf16(af[1], bf[n][1], acc[m][n], 0, 0, 0);
      }
    }
  }

  // epilogue: scores[row] = sum_o tanh(acc + q[o]) * Va[o]
  int c = lane & 15, g4 = lane >> 4;
  float qf[4], vf[4];
#pragma unroll
  for (int n = 0; n < 4; ++n) {
    int o = w * 64 + n * 16 + c;
    qf[n] = q[b * HDIM + o];
    vf[n] = va[o];
  }
#pragma unroll
  for (int m = 0; m < 8; ++m) {
#pragma unroll
    for (int r = 0; r < 4; ++r) {
      float sum = 0.f;
#pragma unroll
      for (int n = 0; n < 4; ++n) sum += fast_tanh(acc[m][n][r] + qf[n]) * vf[n];
      sum += __shfl_xor(sum, 1);
      sum += __shfl_xor(sum, 2);
      sum += __shfl_xor(sum, 4);
      sum += __shfl_xor(sum, 8);
      if (c == 0) atomicAdd(&sc[m * 16 + g4 * 4 + r], sum);
    }
  }
  __syncthreads();

  // partial softmax over the 128 local rows
  float sval = sc[tid & 127];
#pragma unroll
  for (int off = 32; off >= 1; off >>= 1) sval = fmaxf(sval, __shfl_xor(sval, off));
  if ((tid & 63) == 0) red1[w] = sval;
  __syncthreads();
  if (tid == 0) {
    float M = red1[0];
#pragma unroll
    for (int i = 1; i < 8; ++i) M = fmaxf(M, red1[i]);
    bc[0] = M;
  }
  __syncthreads();
  float M = bc[0];
  float pv = 0.f;
  if (tid < BM) {
    pv = __expf(sc[tid] - M);
    pl[tid] = pv;
  }
#pragma unroll
  for (int off = 32; off >= 1; off >>= 1) pv += __shfl_xor(pv, off);
  if ((tid & 63) == 0) red2[w] = pv;
  __syncthreads();
  if (tid == 0) {
    float l = 0.f;
#pragma unroll
    for (int i = 0; i < 8; ++i) l += red2[i];
    mArr[b * NCHUNK + chunk] = M;
    lArr[b * NCHUNK + chunk] = l;
  }
  __syncthreads();

  // partial context: c[h] = sum_rows p[row] * x_ref[row][h] (tile is L2-warm)
  float cacc = 0.f;
#pragma unroll 4
  for (int row = 0; row < BM; ++row) cacc += pl[row] * xb[(long)row * HDIM + tid];
  cpart[((long)b * NCHUNK + chunk) * HDIM + tid] = cacc;
}

__global__ __launch_bounds__(512) void k_combine(const float* __restrict__ mArr,
                                                 const float* __restrict__ lArr,
                                                 const float* __restrict__ cpart,
                                                 float* __restrict__ ctx,
                                                 float* __restrict__ out_ctx) {
  int b = blockIdx.x, t = threadIdx.x;
  __shared__ float wf[NCHUNK];
  __shared__ float dinv;
  if (t == 0) {
    float M = mArr[b * NCHUNK];
    for (int i = 1; i < NCHUNK; ++i) M = fmaxf(M, mArr[b * NCHUNK + i]);
    float den = 0.f;
    for (int i = 0; i < NCHUNK; ++i) {
      float f = __expf(mArr[b * NCHUNK + i] - M);
      wf[i] = f;
      den += f * lArr[b * NCHUNK + i];
    }
    dinv = 1.0f / den;
  }
  __syncthreads();
  float s = 0.f;
#pragma unroll
  for (int i = 0; i < NCHUNK; ++i) s += wf[i] * cpart[((long)b * NCHUNK + i) * HDIM + t];
  float c = s * dinv;
  ctx[b * HDIM + t] = c;
  out_ctx[b * HDIM + t] = c;
}

__global__ __launch_bounds__(512) void k_rnn(const float* __restrict__ xt,
                                             const float* __restrict__ ctx,
                                             const float* __restrict__ hp,
                                             const float* __restrict__ Wih,
                                             const float* __restrict__ Wihb,
                                             const float* __restrict__ Whh,
                                             const float* __restrict__ Whhb,
                                             float* __restrict__ hout) {
  int b = blockIdx.x, o = threadIdx.x;
  __shared__ float xs[EDIM], cs[HDIM], hs[HDIM];
  xs[o] = xt[b * EDIM + o];
  cs[o] = ctx[b * HDIM + o];
  hs[o] = hp[b * HDIM + o];
  __syncthreads();
  const float4* wi = (const float4*)(Wih + (long)o * (EDIM + HDIM));
  float acc = Wihb[o] + Whhb[o];
#pragma unroll 8
  for (int i = 0; i < EDIM / 4; ++i) {
    float4 v = wi[i];
    acc += v.x * xs[i * 4] + v.y * xs[i * 4 + 1] + v.z * xs[i * 4 + 2] + v.w * xs[i * 4 + 3];
  }
  const float4* wi2 = wi + EDIM / 4;
#pragma unroll 8
  for (int i = 0; i < HDIM / 4; ++i) {
    float4 v = wi2[i];
    acc += v.x * cs[i * 4] + v.y * cs[i * 4 + 1] + v.z * cs[i * 4 + 2] + v.w * cs[i * 4 + 3];
  }
  const float4* wh = (const float4*)(Whh + (long)o * HDIM);
#pragma unroll 8
  for (int i = 0; i < HDIM / 4; ++i) {
    float4 v = wh[i];
    acc += v.x * hs[i * 4] + v.y * hs[i * 4 + 1] + v.z * hs[i * 4 + 2] + v.w * hs[i * 4 + 3];
  }
  hout[b * HDIM + o] = tanhf(acc);
}

extern "C" void kernel_launch(void* const* d_in, const int* in_sizes, int n_in,
                              void* d_out, int out_size, void* d_ws, size_t ws_size,
                              hipStream_t stream) {
  const float* x_t    = (const float*)d_in[0];
  const float* x_ref  = (const float*)d_in[1];
  const float* h_prev = (const float*)d_in[2];
  const float* Wa_w   = (const float*)d_in[3];
  const float* Wa_b   = (const float*)d_in[4];
  const float* Ua_w   = (const float*)d_in[5];
  const float* Ua_b   = (const float*)d_in[6];
  const float* Va_w   = (const float*)d_in[7];
  // d_in[8] = Va_b: constant shift before softmax -> no effect, skipped.
  const float* Wih_w  = (const float*)d_in[9];
  const float* Wih_b  = (const float*)d_in[10];
  const float* Whh_w  = (const float*)d_in[11];
  const float* Whh_b  = (const float*)d_in[12];

  char* ws = (char*)d_ws;
  unsigned short* ua_bf = (unsigned short*)ws;       // 512 KB
  float* q     = (float*)(ws + 524288);              // 256 KB
  float* mArr  = (float*)(ws + 786432);              // 8 KB
  float* lArr  = (float*)(ws + 794624);              // 8 KB
  float* cpart = (float*)(ws + 802816);              // 4 MB
  float* ctx   = (float*)(ws + 4997120);             // 256 KB

  float* h_out   = (float*)d_out;
  float* ctx_out = h_out + BDIM * HDIM;

  k_cvt<<<dim3(256), dim3(256), 0, stream>>>(Ua_w, ua_bf, 65536);
  k_q<<<dim3(BDIM), dim3(512), 0, stream>>>(h_prev, Wa_w, Wa_b, Ua_b, q);
  k_scores_ctx<<<dim3(NCHUNK, BDIM), dim3(512), 0, stream>>>(x_ref, ua_bf, q, Va_w, mArr, lArr, cpart);
  k_combine<<<dim3(BDIM), dim3(512), 0, stream>>>(mArr, lArr, cpart, ctx, ctx_out);
  k_rnn<<<dim3(BDIM), dim3(512), 0, stream>>>(x_t, ctx, h_prev, Wih_w, Wih_b, Whh_w, Whh_b, h_out);
}

// Round 2
// 429.851 us; speedup vs baseline: 1.1414x; 1.1414x over previous
//
#include <hip/hip_runtime.h>
#include <hip/hip_bf16.h>
#include <math.h>

// Bahdanau attention + reservoir RNN cell.
//  K0: Ua_w f32 -> bf16 in MFMA B-fragment layout (L2-resident, read direct, no LDS)
//  K1: q = h_prev@Wa^T + Wa_b + Ua_b
//  K2: per (b, 64-row chunk): bf16 MFMA GEMM (A dbuf LDS, B frags from L2),
//      tanh(q+k)·Va -> partial softmax (m,l) + partial context
//  K3: exact combine of 32 partials -> context
//  K4: RNN cell

typedef __attribute__((ext_vector_type(8))) short short8;
typedef __attribute__((ext_vector_type(8))) unsigned short ushort8;
typedef __attribute__((ext_vector_type(4))) unsigned short us4;
typedef __attribute__((ext_vector_type(4))) float f32x4;

#define S_LEN 2048
#define BDIM 128
#define HDIM 512
#define EDIM 512
#define BM 64
#define BK 128
#define NK (HDIM / BK)       // 4
#define NCHUNK (S_LEN / BM)  // 32

__device__ __forceinline__ unsigned short f2bf(float f) {
  unsigned int u = __float_as_uint(f);
  u += 0x7fffu + ((u >> 16) & 1u);  // RNE
  return (unsigned short)(u >> 16);
}

__device__ __forceinline__ float fast_tanh(float x) {
  float e = __expf(2.0f * x);
  return 1.0f - 2.0f / (e + 1.0f);
}

// Ua[512][512] f32 -> bf16 fragment layout:
// frag tile (ct,kt): ct=col/16 (32), kt=k/32 (16); lane l, elem e:
//   col = ct*16 + (l&15), k = kt*32 + (l>>4)*8 + e
// stored at dst[((ct*16+kt)*64 + l)*8 + e]  (1 KB per tile, wave-coalesced)
__global__ __launch_bounds__(256) void k_cvt_b(const float* __restrict__ src,
                                               unsigned short* __restrict__ dst) {
  int tid = blockIdx.x * 256 + threadIdx.x;  // 0..32767
  int ct = tid >> 10;
  int kt = (tid >> 6) & 15;
  int l = tid & 63;
  int col = ct * 16 + (l & 15);
  int k = kt * 32 + (l >> 4) * 8;
  const float4* s = (const float4*)(src + (size_t)col * HDIM + k);
  float4 v0 = s[0], v1 = s[1];
  ushort8 p;
  p[0] = f2bf(v0.x); p[1] = f2bf(v0.y); p[2] = f2bf(v0.z); p[3] = f2bf(v0.w);
  p[4] = f2bf(v1.x); p[5] = f2bf(v1.y); p[6] = f2bf(v1.z); p[7] = f2bf(v1.w);
  *(ushort8*)(dst + (size_t)tid * 8) = p;
}

__global__ __launch_bounds__(512) void k_q(const float* __restrict__ hp,
                                           const float* __restrict__ Wa,
                                           const float* __restrict__ Wab,
                                           const float* __restrict__ Uab,
                                           float* __restrict__ q) {
  int b = blockIdx.x, o = threadIdx.x;
  __shared__ float hs[HDIM];
  hs[o] = hp[b * HDIM + o];
  __syncthreads();
  const float4* wr = (const float4*)(Wa + (long)o * HDIM);
  float acc = 0.f;
#pragma unroll 8
  for (int i = 0; i < HDIM / 4; ++i) {
    float4 v = wr[i];
    acc += v.x * hs[i * 4 + 0] + v.y * hs[i * 4 + 1] + v.z * hs[i * 4 + 2] + v.w * hs[i * 4 + 3];
  }
  q[b * HDIM + o] = acc + Wab[o] + Uab[o];
}

__global__ __launch_bounds__(512, 4) void k_scores_ctx(
    const float* __restrict__ xref, const unsigned short* __restrict__ uab,
    const float* __restrict__ q, const float* __restrict__ va,
    float* __restrict__ mArr, float* __restrict__ lArr, float* __restrict__ cpart) {
  int chunk = blockIdx.x;
  int b = blockIdx.y;
  int tid = threadIdx.x;
  int l = tid & 63;
  int w = tid >> 6;  // 0..7 : wave = 64 output cols

  __shared__ __align__(16) unsigned short As[2][BM * BK];  // 2 x 16 KB, swizzled
  __shared__ float sc[BM];
  __shared__ float pl[BM];
  if (tid < BM) sc[tid] = 0.f;

  f32x4 acc[4][4];
#pragma unroll
  for (int m = 0; m < 4; ++m)
#pragma unroll
    for (int n = 0; n < 4; ++n) acc[m][n] = f32x4{0.f, 0.f, 0.f, 0.f};

  const float* xb = xref + ((size_t)b * S_LEN + (size_t)chunk * BM) * HDIM;

  // staging geometry: 8 threads per row, each 16 consecutive floats
  int srow = tid >> 3, skq = tid & 7;
  const float* sbase = xb + (size_t)srow * HDIM + (size_t)skq * 16;

  float4 r0, r1, r2, r3;

#define LOADC(kc)                                                   \
  {                                                                 \
    const float4* sp = (const float4*)(sbase + (kc) * BK);          \
    r0 = sp[0]; r1 = sp[1]; r2 = sp[2]; r3 = sp[3];                 \
  }

#define WRITEC(buf)                                                 \
  {                                                                 \
    ushort8 p0, p1;                                                 \
    p0[0] = f2bf(r0.x); p0[1] = f2bf(r0.y); p0[2] = f2bf(r0.z);     \
    p0[3] = f2bf(r0.w); p0[4] = f2bf(r1.x); p0[5] = f2bf(r1.y);     \
    p0[6] = f2bf(r1.z); p0[7] = f2bf(r1.w);                         \
    p1[0] = f2bf(r2.x); p1[1] = f2bf(r2.y); p1[2] = f2bf(r2.z);     \
    p1[3] = f2bf(r2.w); p1[4] = f2bf(r3.x); p1[5] = f2bf(r3.y);     \
    p1[6] = f2bf(r3.z); p1[7] = f2bf(r3.w);                         \
    int s0 = (2 * skq) ^ (srow & 7), s1 = (2 * skq + 1) ^ (srow & 7); \
    *(ushort8*)&As[buf][srow * BK + s0 * 8] = p0;                   \
    *(ushort8*)&As[buf][srow * BK + s1 * 8] = p1;                   \
  }

  LOADC(0);
  WRITEC(0);
  __syncthreads();

#pragma unroll
  for (int kc = 0; kc < NK; ++kc) {
    if (kc < NK - 1) LOADC(kc + 1);
#pragma unroll
    for (int kk = 0; kk < 4; ++kk) {
      short8 a[4], bfr[4];
#pragma unroll
      for (int m = 0; m < 4; ++m) {
        int row = m * 16 + (l & 15);
        int sw = (kk * 4 + (l >> 4)) ^ (row & 7);
        a[m] = *(const short8*)&As[kc & 1][row * BK + sw * 8];
      }
#pragma unroll
      for (int n = 0; n < 4; ++n) {
        int ct = w * 4 + n, kt = kc * 4 + kk;
        bfr[n] = *(const short8*)(uab + (((size_t)(ct * 16 + kt) * 64 + l) * 8));
      }
#pragma unroll
      for (int m = 0; m < 4; ++m)
#pragma unroll
        for (int n = 0; n < 4; ++n)
          acc[m][n] = __builtin_amdgcn_mfma_f32_16x16x32_bf16(a[m], bfr[n], acc[m][n], 0, 0, 0);
    }
    if (kc < NK - 1) WRITEC((kc + 1) & 1);
    __syncthreads();
  }

  // epilogue: scores[row] = sum_o tanh(acc + q[o]) * Va[o]
  int c = l & 15, g4 = l >> 4;
  float qf[4], vf[4];
#pragma unroll
  for (int n = 0; n < 4; ++n) {
    int o = w * 64 + n * 16 + c;
    qf[n] = q[b * HDIM + o];
    vf[n] = va[o];
  }
#pragma unroll
  for (int m = 0; m < 4; ++m) {
#pragma unroll
    for (int r = 0; r < 4; ++r) {
      float sum = 0.f;
#pragma unroll
      for (int n = 0; n < 4; ++n) sum += fast_tanh(acc[m][n][r] + qf[n]) * vf[n];
      sum += __shfl_xor(sum, 1);
      sum += __shfl_xor(sum, 2);
      sum += __shfl_xor(sum, 4);
      sum += __shfl_xor(sum, 8);
      if (c == 0) atomicAdd(&sc[m * 16 + g4 * 4 + r], sum);
    }
  }
  __syncthreads();

  // partial softmax over the 64 local rows (each wave computes same values)
  float M = sc[l];
#pragma unroll
  for (int off = 32; off >= 1; off >>= 1) M = fmaxf(M, __shfl_xor(M, off));
  float p = __expf(sc[l] - M);
  float lsum = p;
#pragma unroll
  for (int off = 32; off >= 1; off >>= 1) lsum += __shfl_xor(lsum, off);
  if (tid < BM) pl[tid] = p;
  if (tid == 0) {
    mArr[b * NCHUNK + chunk] = M;
    lArr[b * NCHUNK + chunk] = lsum;
  }
  __syncthreads();

  // partial context (tile is L2-warm from staging)
  float cacc = 0.f;
#pragma unroll 8
  for (int row = 0; row < BM; ++row) cacc += pl[row] * xb[(size_t)row * HDIM + tid];
  cpart[((size_t)b * NCHUNK + chunk) * HDIM + tid] = cacc;
#undef LOADC
#undef WRITEC
}

__global__ __launch_bounds__(512) void k_combine(const float* __restrict__ mArr,
                                                 const float* __restrict__ lArr,
                                                 const float* __restrict__ cpart,
                                                 float* __restrict__ ctx,
                                                 float* __restrict__ out_ctx) {
  int b = blockIdx.x, t = threadIdx.x;
  __shared__ float wf[NCHUNK];
  __shared__ float dinv;
  if (t == 0) {
    float M = mArr[b * NCHUNK];
    for (int i = 1; i < NCHUNK; ++i) M = fmaxf(M, mArr[b * NCHUNK + i]);
    float den = 0.f;
    for (int i = 0; i < NCHUNK; ++i) {
      float f = __expf(mArr[b * NCHUNK + i] - M);
      wf[i] = f;
      den += f * lArr[b * NCHUNK + i];
    }
    dinv = 1.0f / den;
  }
  __syncthreads();
  float s = 0.f;
#pragma unroll
  for (int i = 0; i < NCHUNK; ++i) s += wf[i] * cpart[((size_t)b * NCHUNK + i) * HDIM + t];
  float c = s * dinv;
  ctx[b * HDIM + t] = c;
  out_ctx[b * HDIM + t] = c;
}

__global__ __launch_bounds__(512) void k_rnn(const float* __restrict__ xt,
                                             const float* __restrict__ ctx,
                                             const float* __restrict__ hp,
                                             const float* __restrict__ Wih,
                                             const float* __restrict__ Wihb,
                                             const float* __restrict__ Whh,
                                             const float* __restrict__ Whhb,
                                             float* __restrict__ hout) {
  int b = blockIdx.x, o = threadIdx.x;
  __shared__ float xs[EDIM], cs[HDIM], hs[HDIM];
  xs[o] = xt[b * EDIM + o];
  cs[o] = ctx[b * HDIM + o];
  hs[o] = hp[b * HDIM + o];
  __syncthreads();
  const float4* wi = (const float4*)(Wih + (long)o * (EDIM + HDIM));
  float acc = Wihb[o] + Whhb[o];
#pragma unroll 8
  for (int i = 0; i < EDIM / 4; ++i) {
    float4 v = wi[i];
    acc += v.x * xs[i * 4] + v.y * xs[i * 4 + 1] + v.z * xs[i * 4 + 2] + v.w * xs[i * 4 + 3];
  }
  const float4* wi2 = wi + EDIM / 4;
#pragma unroll 8
  for (int i = 0; i < HDIM / 4; ++i) {
    float4 v = wi2[i];
    acc += v.x * cs[i * 4] + v.y * cs[i * 4 + 1] + v.z * cs[i * 4 + 2] + v.w * cs[i * 4 + 3];
  }
  const float4* wh = (const float4*)(Whh + (long)o * HDIM);
#pragma unroll 8
  for (int i = 0; i < HDIM / 4; ++i) {
    float4 v = wh[i];
    acc += v.x * hs[i * 4] + v.y * hs[i * 4 + 1] + v.z * hs[i * 4 + 2] + v.w * hs[i * 4 + 3];
  }
  hout[b * HDIM + o] = tanhf(acc);
}

extern "C" void kernel_launch(void* const* d_in, const int* in_sizes, int n_in,
                              void* d_out, int out_size, void* d_ws, size_t ws_size,
                              hipStream_t stream) {
  const float* x_t    = (const float*)d_in[0];
  const float* x_ref  = (const float*)d_in[1];
  const float* h_prev = (const float*)d_in[2];
  const float* Wa_w   = (const float*)d_in[3];
  const float* Wa_b   = (const float*)d_in[4];
  const float* Ua_w   = (const float*)d_in[5];
  const float* Ua_b   = (const float*)d_in[6];
  const float* Va_w   = (const float*)d_in[7];
  // d_in[8] = Va_b: softmax-invariant, skipped.
  const float* Wih_w  = (const float*)d_in[9];
  const float* Wih_b  = (const float*)d_in[10];
  const float* Whh_w  = (const float*)d_in[11];
  const float* Whh_b  = (const float*)d_in[12];

  char* ws = (char*)d_ws;
  unsigned short* ua_fr = (unsigned short*)ws;   // 512 KB fragment-layout Ua
  float* q     = (float*)(ws + 524288);          // 256 KB
  float* mArr  = (float*)(ws + 786432);          // 16 KB
  float* lArr  = (float*)(ws + 802816);          // 16 KB
  float* cpart = (float*)(ws + 819200);          // 8 MB
  float* ctx   = (float*)(ws + 9207808);         // 256 KB

  float* h_out   = (float*)d_out;
  float* ctx_out = h_out + BDIM * HDIM;

  k_cvt_b<<<dim3(128), dim3(256), 0, stream>>>(Ua_w, ua_fr);
  k_q<<<dim3(BDIM), dim3(512), 0, stream>>>(h_prev, Wa_w, Wa_b, Ua_b, q);
  k_scores_ctx<<<dim3(NCHUNK, BDIM), dim3(512), 0, stream>>>(x_ref, ua_fr, q, Va_w, mArr, lArr, cpart);
  k_combine<<<dim3(BDIM), dim3(512), 0, stream>>>(mArr, lArr, cpart, ctx, ctx_out);
  k_rnn<<<dim3(BDIM), dim3(512), 0, stream>>>(x_t, ctx, h_prev, Wih_w, Wih_b, Whh_w, Whh_b, h_out);
}

// Round 3
// 353.982 us; speedup vs baseline: 1.3861x; 1.2143x over previous
//
#include <hip/hip_runtime.h>
#include <hip/hip_bf16.h>
#include <math.h>

// Bahdanau attention + reservoir RNN cell.
//  K0: Ua_w f32 -> bf16 in MFMA B-fragment layout (L2-resident, read direct)
//  K1: q = h_prev@Wa^T + Wa_b + Ua_b
//  K2: per (b, 64-row chunk): bf16 MFMA GEMM. A: full 64KB LDS tile, 4 disjoint
//      kc regions, T14 issue-early/write-late staging, zero-conflict swizzle.
//      B: fragment-layout from L2. Epilogue: tanh(q+k)·Va -> partial softmax
//      (m,l) + partial context from the bf16 LDS tile.
//  K3: exact combine of 32 partials -> context
//  K4: RNN cell (grid split over o for full-chip coverage)

typedef __attribute__((ext_vector_type(8))) short short8;
typedef __attribute__((ext_vector_type(8))) unsigned short ushort8;
typedef __attribute__((ext_vector_type(4))) float f32x4;

#define S_LEN 2048
#define BDIM 128
#define HDIM 512
#define EDIM 512
#define BM 64
#define BK 128
#define NK (HDIM / BK)       // 4
#define NCHUNK (S_LEN / BM)  // 32

__device__ __forceinline__ unsigned short f2bf(float f) {
  unsigned int u = __float_as_uint(f);
  u += 0x7fffu + ((u >> 16) & 1u);  // RNE
  return (unsigned short)(u >> 16);
}

__device__ __forceinline__ float bf2f(unsigned short u) {
  return __uint_as_float(((unsigned int)u) << 16);
}

__device__ __forceinline__ float fast_tanh(float x) {
  float e = __expf(2.0f * x);
  return 1.0f - 2.0f / (e + 1.0f);
}

// Ua[512][512] f32 -> bf16 fragment layout:
// tile (ct,kt): col = ct*16 + (l&15), k = kt*32 + (l>>4)*8 + e
// at dst[((ct*16+kt)*64 + l)*8 + e]
__global__ __launch_bounds__(256) void k_cvt_b(const float* __restrict__ src,
                                               unsigned short* __restrict__ dst) {
  int tid = blockIdx.x * 256 + threadIdx.x;  // 0..32767
  int ct = tid >> 10;
  int kt = (tid >> 6) & 15;
  int l = tid & 63;
  int col = ct * 16 + (l & 15);
  int k = kt * 32 + (l >> 4) * 8;
  const float4* s = (const float4*)(src + (size_t)col * HDIM + k);
  float4 v0 = s[0], v1 = s[1];
  ushort8 p;
  p[0] = f2bf(v0.x); p[1] = f2bf(v0.y); p[2] = f2bf(v0.z); p[3] = f2bf(v0.w);
  p[4] = f2bf(v1.x); p[5] = f2bf(v1.y); p[6] = f2bf(v1.z); p[7] = f2bf(v1.w);
  *(ushort8*)(dst + (size_t)tid * 8) = p;
}

__global__ __launch_bounds__(256) void k_q(const float* __restrict__ hp,
                                           const float* __restrict__ Wa,
                                           const float* __restrict__ Wab,
                                           const float* __restrict__ Uab,
                                           float* __restrict__ q) {
  int b = blockIdx.x, oh = blockIdx.y;
  int o = oh * 256 + threadIdx.x;
  __shared__ float hs[HDIM];
  hs[threadIdx.x] = hp[b * HDIM + threadIdx.x];
  hs[threadIdx.x + 256] = hp[b * HDIM + threadIdx.x + 256];
  __syncthreads();
  const float4* wr = (const float4*)(Wa + (size_t)o * HDIM);
  float acc = 0.f;
#pragma unroll 8
  for (int i = 0; i < HDIM / 4; ++i) {
    float4 v = wr[i];
    acc += v.x * hs[i * 4 + 0] + v.y * hs[i * 4 + 1] + v.z * hs[i * 4 + 2] + v.w * hs[i * 4 + 3];
  }
  q[b * HDIM + o] = acc + Wab[o] + Uab[o];
}

__global__ __launch_bounds__(512, 4) void k_scores_ctx(
    const float* __restrict__ xref, const unsigned short* __restrict__ uab,
    const float* __restrict__ q, const float* __restrict__ va,
    float* __restrict__ mArr, float* __restrict__ lArr, float* __restrict__ cpart) {
  int chunk = blockIdx.x;
  int b = blockIdx.y;
  int tid = threadIdx.x;
  int l = tid & 63;
  int w = tid >> 6;   // 0..7, wave owns 64 output cols
  int q4 = l >> 4;

  __shared__ __align__(16) unsigned short As[BM * HDIM];  // 64 KB, swizzled bf16
  __shared__ float sc[BM];
  __shared__ float pl[BM];
  if (tid < BM) sc[tid] = 0.f;

  f32x4 acc[4][4];
#pragma unroll
  for (int m = 0; m < 4; ++m)
#pragma unroll
    for (int n = 0; n < 4; ++n) acc[m][n] = f32x4{0.f, 0.f, 0.f, 0.f};

  const float* xb = xref + ((size_t)b * S_LEN + (size_t)chunk * BM) * HDIM;

  // staging: 8 threads per row; thread covers k-slots skq and skq+8 of the kc tile
  int srow = tid >> 3, skq = tid & 7;
  int slotA = skq ^ (srow & 7);
  const float* sbase = xb + (size_t)srow * HDIM + (size_t)skq * 8;

  float4 xa0, xa1, xb0, xb1;

#define LOADKC(kc)                                      \
  {                                                     \
    const float* bp = sbase + (kc) * BK;                \
    xa0 = ((const float4*)bp)[0];                       \
    xa1 = ((const float4*)bp)[1];                       \
    xb0 = ((const float4*)(bp + 64))[0];                \
    xb1 = ((const float4*)(bp + 64))[1];                \
  }

#define WRITEKC(kc)                                                    \
  {                                                                    \
    ushort8 pA, pB;                                                    \
    pA[0] = f2bf(xa0.x); pA[1] = f2bf(xa0.y); pA[2] = f2bf(xa0.z);     \
    pA[3] = f2bf(xa0.w); pA[4] = f2bf(xa1.x); pA[5] = f2bf(xa1.y);     \
    pA[6] = f2bf(xa1.z); pA[7] = f2bf(xa1.w);                          \
    pB[0] = f2bf(xb0.x); pB[1] = f2bf(xb0.y); pB[2] = f2bf(xb0.z);     \
    pB[3] = f2bf(xb0.w); pB[4] = f2bf(xb1.x); pB[5] = f2bf(xb1.y);     \
    pB[6] = f2bf(xb1.z); pB[7] = f2bf(xb1.w);                          \
    int base = srow * HDIM + (kc) * BK + slotA * 8;                    \
    *(ushort8*)&As[base] = pA;                                         \
    *(ushort8*)&As[base + 64] = pB;                                    \
  }

#define COMPUTEKC(kc)                                                          \
  {                                                                            \
    _Pragma("unroll")                                                          \
    for (int kk = 0; kk < 4; ++kk) {                                           \
      short8 afr[4], bfr[4];                                                   \
      int j = kk * 4 + q4;                                                     \
      _Pragma("unroll")                                                        \
      for (int m = 0; m < 4; ++m) {                                            \
        int row = m * 16 + (l & 15);                                           \
        int P = (j & 8) | ((j & 7) ^ (row & 7));                               \
        afr[m] = *(const short8*)&As[row * HDIM + (kc) * BK + P * 8];          \
      }                                                                        \
      _Pragma("unroll")                                                        \
      for (int n = 0; n < 4; ++n) {                                            \
        int ct = w * 4 + n, kt = (kc) * 4 + kk;                                \
        bfr[n] = *(const short8*)(uab + (((size_t)(ct * 16 + kt) * 64 + l) * 8)); \
      }                                                                        \
      __builtin_amdgcn_s_setprio(1);                                           \
      _Pragma("unroll")                                                        \
      for (int m = 0; m < 4; ++m)                                              \
        _Pragma("unroll")                                                      \
        for (int n = 0; n < 4; ++n)                                            \
          acc[m][n] = __builtin_amdgcn_mfma_f32_16x16x32_bf16(afr[m], bfr[n],  \
                                                              acc[m][n], 0, 0, 0); \
      __builtin_amdgcn_s_setprio(0);                                           \
    }                                                                          \
  }

  LOADKC(0);
  WRITEKC(0);
  __syncthreads();

  LOADKC(1);
  COMPUTEKC(0);
  WRITEKC(1);
  __syncthreads();

  LOADKC(2);
  COMPUTEKC(1);
  WRITEKC(2);
  __syncthreads();

  LOADKC(3);
  COMPUTEKC(2);
  WRITEKC(3);
  __syncthreads();

  // hoist q/Va loads under the last compute phase
  int c = l & 15, g4 = l >> 4;
  float qf[4], vf[4];
#pragma unroll
  for (int n = 0; n < 4; ++n) {
    int o = w * 64 + n * 16 + c;
    qf[n] = q[b * HDIM + o];
    vf[n] = va[o];
  }
  COMPUTEKC(3);

  // scores[row] = sum_o tanh(acc + q[o]) * Va[o]
#pragma unroll
  for (int m = 0; m < 4; ++m) {
#pragma unroll
    for (int r = 0; r < 4; ++r) {
      float sum = 0.f;
#pragma unroll
      for (int n = 0; n < 4; ++n) sum += fast_tanh(acc[m][n][r] + qf[n]) * vf[n];
      sum += __shfl_xor(sum, 1);
      sum += __shfl_xor(sum, 2);
      sum += __shfl_xor(sum, 4);
      sum += __shfl_xor(sum, 8);
      if (c == 0) atomicAdd(&sc[m * 16 + g4 * 4 + r], sum);
    }
  }
  __syncthreads();

  // partial softmax over the 64 local rows
  float M = sc[l];
#pragma unroll
  for (int off = 32; off >= 1; off >>= 1) M = fmaxf(M, __shfl_xor(M, off));
  float p = __expf(sc[l] - M);
  float lsum = p;
#pragma unroll
  for (int off = 32; off >= 1; off >>= 1) lsum += __shfl_xor(lsum, off);
  if (tid < BM) pl[tid] = p;
  if (tid == 0) {
    mArr[b * NCHUNK + chunk] = M;
    lArr[b * NCHUNK + chunk] = lsum;
  }
  __syncthreads();

  // partial context from the bf16 LDS tile (no global re-read)
  {
    int kc_t = tid >> 7;
    int jj = (tid >> 3) & 15;
    int e = tid & 7;
    int base = kc_t * BK + (jj & 8) * 8 + e;  // (j&8) part of P is row-independent
    int jl = jj & 7;
    float cacc = 0.f;
#pragma unroll 8
    for (int r = 0; r < BM; ++r) {
      int P_low = jl ^ (r & 7);
      cacc += pl[r] * bf2f(As[r * HDIM + base + P_low * 8]);
    }
    cpart[((size_t)b * NCHUNK + chunk) * HDIM + tid] = cacc;
  }
#undef LOADKC
#undef WRITEKC
#undef COMPUTEKC
}

__global__ __launch_bounds__(512) void k_combine(const float* __restrict__ mArr,
                                                 const float* __restrict__ lArr,
                                                 const float* __restrict__ cpart,
                                                 float* __restrict__ ctx,
                                                 float* __restrict__ out_ctx) {
  int b = blockIdx.x, t = threadIdx.x;
  __shared__ float wf[NCHUNK];
  __shared__ float dinv;
  if (t == 0) {
    float M = mArr[b * NCHUNK];
    for (int i = 1; i < NCHUNK; ++i) M = fmaxf(M, mArr[b * NCHUNK + i]);
    float den = 0.f;
    for (int i = 0; i < NCHUNK; ++i) {
      float f = __expf(mArr[b * NCHUNK + i] - M);
      wf[i] = f;
      den += f * lArr[b * NCHUNK + i];
    }
    dinv = 1.0f / den;
  }
  __syncthreads();
  float s = 0.f;
#pragma unroll
  for (int i = 0; i < NCHUNK; ++i) s += wf[i] * cpart[((size_t)b * NCHUNK + i) * HDIM + t];
  float c = s * dinv;
  ctx[b * HDIM + t] = c;
  out_ctx[b * HDIM + t] = c;
}

__global__ __launch_bounds__(256) void k_rnn(const float* __restrict__ xt,
                                             const float* __restrict__ ctx,
                                             const float* __restrict__ hp,
                                             const float* __restrict__ Wih,
                                             const float* __restrict__ Wihb,
                                             const float* __restrict__ Whh,
                                             const float* __restrict__ Whhb,
                                             float* __restrict__ hout) {
  int b = blockIdx.x, oh = blockIdx.y;
  int o = oh * 256 + threadIdx.x;
  __shared__ float xs[EDIM], cs[HDIM], hs[HDIM];
  xs[threadIdx.x] = xt[b * EDIM + threadIdx.x];
  xs[threadIdx.x + 256] = xt[b * EDIM + threadIdx.x + 256];
  cs[threadIdx.x] = ctx[b * HDIM + threadIdx.x];
  cs[threadIdx.x + 256] = ctx[b * HDIM + threadIdx.x + 256];
  hs[threadIdx.x] = hp[b * HDIM + threadIdx.x];
  hs[threadIdx.x + 256] = hp[b * HDIM + threadIdx.x + 256];
  __syncthreads();
  const float4* wi = (const float4*)(Wih + (size_t)o * (EDIM + HDIM));
  float acc = Wihb[o] + Whhb[o];
#pragma unroll 8
  for (int i = 0; i < EDIM / 4; ++i) {
    float4 v = wi[i];
    acc += v.x * xs[i * 4] + v.y * xs[i * 4 + 1] + v.z * xs[i * 4 + 2] + v.w * xs[i * 4 + 3];
  }
  const float4* wi2 = wi + EDIM / 4;
#pragma unroll 8
  for (int i = 0; i < HDIM / 4; ++i) {
    float4 v = wi2[i];
    acc += v.x * cs[i * 4] + v.y * cs[i * 4 + 1] + v.z * cs[i * 4 + 2] + v.w * cs[i * 4 + 3];
  }
  const float4* wh = (const float4*)(Whh + (size_t)o * HDIM);
#pragma unroll 8
  for (int i = 0; i < HDIM / 4; ++i) {
    float4 v = wh[i];
    acc += v.x * hs[i * 4] + v.y * hs[i * 4 + 1] + v.z * hs[i * 4 + 2] + v.w * hs[i * 4 + 3];
  }
  hout[b * HDIM + o] = tanhf(acc);
}

extern "C" void kernel_launch(void* const* d_in, const int* in_sizes, int n_in,
                              void* d_out, int out_size, void* d_ws, size_t ws_size,
                              hipStream_t stream) {
  const float* x_t    = (const float*)d_in[0];
  const float* x_ref  = (const float*)d_in[1];
  const float* h_prev = (const float*)d_in[2];
  const float* Wa_w   = (const float*)d_in[3];
  const float* Wa_b   = (const float*)d_in[4];
  const float* Ua_w   = (const float*)d_in[5];
  const float* Ua_b   = (const float*)d_in[6];
  const float* Va_w   = (const float*)d_in[7];
  // d_in[8] = Va_b: softmax-invariant, skipped.
  const float* Wih_w  = (const float*)d_in[9];
  const float* Wih_b  = (const float*)d_in[10];
  const float* Whh_w  = (const float*)d_in[11];
  const float* Whh_b  = (const float*)d_in[12];

  char* ws = (char*)d_ws;
  unsigned short* ua_fr = (unsigned short*)ws;   // 512 KB fragment-layout Ua
  float* q     = (float*)(ws + 524288);          // 256 KB
  float* mArr  = (float*)(ws + 786432);          // 16 KB
  float* lArr  = (float*)(ws + 802816);          // 16 KB
  float* cpart = (float*)(ws + 819200);          // 8 MB
  float* ctx   = (float*)(ws + 9207808);         // 256 KB

  float* h_out   = (float*)d_out;
  float* ctx_out = h_out + BDIM * HDIM;

  k_cvt_b<<<dim3(128), dim3(256), 0, stream>>>(Ua_w, ua_fr);
  k_q<<<dim3(BDIM, 2), dim3(256), 0, stream>>>(h_prev, Wa_w, Wa_b, Ua_b, q);
  k_scores_ctx<<<dim3(NCHUNK, BDIM), dim3(512), 0, stream>>>(x_ref, ua_fr, q, Va_w, mArr, lArr, cpart);
  k_combine<<<dim3(BDIM), dim3(512), 0, stream>>>(mArr, lArr, cpart, ctx, ctx_out);
  k_rnn<<<dim3(BDIM, 2), dim3(256), 0, stream>>>(x_t, ctx, h_prev, Wih_w, Wih_b, Whh_w, Whh_b, h_out);
}